// Round 14
// baseline (1162.173 us; speedup 1.0000x reference)
//
#include <hip/hip_runtime.h>
#include <hip/hip_bf16.h>

// LSTM H=1024, B=256, T=256, C=10 — round 14.
// Round 13: lcl=false (WRITE_SIZE unchanged 265MB) => blockIdx&7 grouping is
// NOT XCD-uniform; IC staging (16 MB/step, 32x amplification) remains the
// dominant term. Round 14 derives the grouping FROM hardware: each WG claims
// slot=ctrl[xcc]++ at the IC, rendezvous on done==256 (co-residency of all
// 256 WGs is the same property the per-step barrier has relied on since
// round 5; capacity: 101KB LDS -> 1 WG/CU -> all CUs filled -> exactly
// 32 WGs/XCD), then every WG independently computes the same verdict.
// mode1 (expected): bt=xcc, jt=slot -> h exchange is physically XCD-local:
//   plain write-back h stores + sc0 staging loads (per-XCD L2, ~0.5us/step
//   vs ~1.5-2us IC). Flags REMAIN on the IC path (L2-resident flag stamps
//   are unsafe across graph replays: stale dirty lines survive memset; frag
//   lines are safe since every byte is rewritten each step before the flag).
// mode2: byte-identical round-13 IC fallback (proven).

#define H 1024
#define B 256
#define T 256
#define NCLS 10

typedef __attribute__((ext_vector_type(8))) short short8;   // 8 bf16
typedef __attribute__((ext_vector_type(4))) float f32x4;

__device__ inline unsigned short bf16_bits(float f) {
    union { __hip_bfloat16 h; unsigned short u; } cv;
    cv.h = __float2bfloat16(f);
    return cv.u;
}

#define L2E 1.4426950408889634f
__device__ inline float sigm_fast(float x) {
    float e = __builtin_amdgcn_exp2f(-L2E * x);
    return __builtin_amdgcn_rcpf(1.0f + e);
}
__device__ inline float tanh_fast(float x) {
    float e = __builtin_amdgcn_exp2f((2.0f * L2E) * x);     // e^(2x)
    return 1.0f - 2.0f * __builtin_amdgcn_rcpf(1.0f + e);   // +-sat correct
}

// h frag layout (per 512 KB buffer), 16x16x32 B-frag order:
//   short index of (j in [0,1024), b in [0,256)):
//   ((b>>4)*32 + (j>>5))*512 + (((j>>3)&3)*16 + (b&15))*8 + (j&7)

__global__ __launch_bounds__(512)
__attribute__((amdgpu_waves_per_eu(2, 2)))
void lstm_persist(
    const float* __restrict__ x,
    const float* __restrict__ Wgh, const float* __restrict__ Wih,
    const float* __restrict__ Wfh, const float* __restrict__ Woh,
    const float* __restrict__ Wgx, const float* __restrict__ Wix,
    const float* __restrict__ Wfx, const float* __restrict__ Wox,
    const float* __restrict__ bg, const float* __restrict__ bi,
    const float* __restrict__ bf_, const float* __restrict__ bo,
    char* __restrict__ frag,            // 2 x 524288 bytes (no init needed)
    unsigned* __restrict__ flags,       // 256 flag lines, 128-B stride (IC)
    unsigned* __restrict__ ctrl,        // [0..7]=claim, [8]=done (IC, zeroed)
    float* __restrict__ hfin)           // H x B fp32
{
    __shared__ __align__(16) char hstage[65536];   // full bt h-slice (64 KB)
    __shared__ float zb[2][4][32][36];             // [khalf][gate][row][col+pad]
    __shared__ float wxl[4][32];
    __shared__ float bsl[4][32];
    __shared__ int sh_bt, sh_jt, sh_lcl;

    const int tid  = threadIdx.x;
    const int lane = tid & 63;
    const int wave = tid >> 6;          // 0..7
    const int gate = wave & 3;
    const int kh   = wave >> 2;         // k-half

    // ---- one-time: claim a slot on my physical XCD, rendezvous, verdict ----
    if (tid == 0) {
        unsigned xcc;
        __asm__ volatile("s_getreg_b32 %0, hwreg(HW_REG_XCC_ID)" : "=s"(xcc));
        xcc &= 7u;
        unsigned slot = __hip_atomic_fetch_add(&ctrl[xcc], 1u,
                            __ATOMIC_RELAXED, __HIP_MEMORY_SCOPE_AGENT);
        __hip_atomic_fetch_add(&ctrl[8], 1u,
                            __ATOMIC_RELAXED, __HIP_MEMORY_SCOPE_AGENT);
        // all 256 WGs are co-resident (same property the per-step barrier
        // depends on, proven rounds 5-13) -> this poll terminates
        while (__hip_atomic_load(&ctrl[8], __ATOMIC_RELAXED,
                                 __HIP_MEMORY_SCOPE_AGENT) < 256u)
            __builtin_amdgcn_s_sleep(2);
        bool ok = true;
        for (int i = 0; i < 8; ++i) {
            unsigned c = __hip_atomic_load(&ctrl[i], __ATOMIC_RELAXED,
                                           __HIP_MEMORY_SCOPE_AGENT);
            ok &= (c == 32u);
        }
        if (ok) { sh_bt = (int)xcc; sh_jt = (int)slot; sh_lcl = 1; }
        else    { sh_bt = blockIdx.x & 7; sh_jt = blockIdx.x >> 3; sh_lcl = 0; }
    }
    __syncthreads();
    const int  bt  = sh_bt;
    const int  jt  = sh_jt;
    const bool lcl = (sh_lcl != 0);
    const int  j0  = jt * 32;
    const int  b0  = bt * 32;

    if (tid < 128) {
        int g = tid >> 5, r = tid & 31;
        const float* wx = (g == 0) ? Wgx : (g == 1) ? Wix : (g == 2) ? Wfx : Wox;
        const float* bb = (g == 0) ? bg  : (g == 1) ? bi  : (g == 2) ? bf_ : bo;
        wxl[g][r] = wx[j0 + r];
        bsl[g][r] = bb[b0 + r];
    }

    // ---- one-time: W gate tile -> registers, 16x16x32 A-fragment order ----
    const float* Wh = (gate == 0) ? Wgh : (gate == 1) ? Wih : (gate == 2) ? Wfh : Woh;
    short8 awreg[2][16];
#pragma unroll
    for (int mt = 0; mt < 2; ++mt) {
        const float* wrow = Wh + (j0 + 16 * mt + (lane & 15)) * H
                          + kh * 512 + ((lane >> 4) * 8);
#pragma unroll
        for (int c = 0; c < 16; ++c) {
            const float4 f0 = *(const float4*)(wrow + c * 32);
            const float4 f1 = *(const float4*)(wrow + c * 32 + 4);
            short8 s;
            s[0] = (short)bf16_bits(f0.x); s[1] = (short)bf16_bits(f0.y);
            s[2] = (short)bf16_bits(f0.z); s[3] = (short)bf16_bits(f0.w);
            s[4] = (short)bf16_bits(f1.x); s[5] = (short)bf16_bits(f1.y);
            s[6] = (short)bf16_bits(f1.z); s[7] = (short)bf16_bits(f1.w);
            awreg[mt][c] = s;
        }
    }
#pragma unroll
    for (int mt = 0; mt < 2; ++mt)
#pragma unroll
        for (int c = 0; c < 16; ++c)
            __asm__ volatile("" : "+a"(awreg[mt][c]));

    float creg[2] = {0.f, 0.f};
    const int nn = tid & 31;
    const int aa = tid >> 5;

    // flags indexed by (bt,jt) — unique per WG in both modes; always IC
    unsigned* myflag = &flags[(bt * 32 + jt) * 32];
    unsigned* pollflag = &flags[(bt * 32 + (lane & 31)) * 32];

    for (int t = 0; t < T; ++t) {
        const float xv = x[(b0 + nn) * T + t];

        // ---- wait (IC protocol, rounds 11-13, unchanged) ----
        if (wave == 0) {
            const unsigned target = (unsigned)t;
            while (true) {
                unsigned v = __hip_atomic_load(pollflag, __ATOMIC_RELAXED,
                                               __HIP_MEMORY_SCOPE_AGENT);
                if (__all((int)(v >= target))) break;
                __builtin_amdgcn_s_sleep(1);
            }
        }
        __syncthreads();

        f32x4 a00 = {0.f,0.f,0.f,0.f}, a01 = a00, a10 = a00, a11 = a00;

        if (t > 0) {        // h_0 == 0 -> z == 0: skip staging+MFMA at t=0
            {
                const char* gbase = frag + (t & 1) * 524288 + bt * 65536 + tid * 16;
                short8 v0, v1, v2, v3, v4, v5, v6, v7;
                if (lcl) {   // XCD-local: L2 exchange (sc0 = L1 bypass only)
                    __asm__ volatile(
                        "global_load_dwordx4 %0, %8, off sc0\n\t"
                        "global_load_dwordx4 %1, %9, off sc0\n\t"
                        "global_load_dwordx4 %2, %10, off sc0\n\t"
                        "global_load_dwordx4 %3, %11, off sc0\n\t"
                        "global_load_dwordx4 %4, %12, off sc0\n\t"
                        "global_load_dwordx4 %5, %13, off sc0\n\t"
                        "global_load_dwordx4 %6, %14, off sc0\n\t"
                        "global_load_dwordx4 %7, %15, off sc0\n\t"
                        "s_waitcnt vmcnt(0)"
                        : "=&v"(v0), "=&v"(v1), "=&v"(v2), "=&v"(v3),
                          "=&v"(v4), "=&v"(v5), "=&v"(v6), "=&v"(v7)
                        : "v"(gbase),         "v"(gbase + 8192),
                          "v"(gbase + 16384), "v"(gbase + 24576),
                          "v"(gbase + 32768), "v"(gbase + 40960),
                          "v"(gbase + 49152), "v"(gbase + 57344)
                        : "memory");
                } else {     // IC path (proven)
                    __asm__ volatile(
                        "global_load_dwordx4 %0, %8, off sc0 sc1\n\t"
                        "global_load_dwordx4 %1, %9, off sc0 sc1\n\t"
                        "global_load_dwordx4 %2, %10, off sc0 sc1\n\t"
                        "global_load_dwordx4 %3, %11, off sc0 sc1\n\t"
                        "global_load_dwordx4 %4, %12, off sc0 sc1\n\t"
                        "global_load_dwordx4 %5, %13, off sc0 sc1\n\t"
                        "global_load_dwordx4 %6, %14, off sc0 sc1\n\t"
                        "global_load_dwordx4 %7, %15, off sc0 sc1\n\t"
                        "s_waitcnt vmcnt(0)"
                        : "=&v"(v0), "=&v"(v1), "=&v"(v2), "=&v"(v3),
                          "=&v"(v4), "=&v"(v5), "=&v"(v6), "=&v"(v7)
                        : "v"(gbase),         "v"(gbase + 8192),
                          "v"(gbase + 16384), "v"(gbase + 24576),
                          "v"(gbase + 32768), "v"(gbase + 40960),
                          "v"(gbase + 49152), "v"(gbase + 57344)
                        : "memory");
                }
                short8* dd = (short8*)hstage;
                dd[tid +    0] = v0;  dd[tid +  512] = v1;
                dd[tid + 1024] = v2;  dd[tid + 1536] = v3;
                dd[tid + 2048] = v4;  dd[tid + 2560] = v5;
                dd[tid + 3072] = v6;  dd[tid + 3584] = v7;
            }
            __syncthreads();

#pragma unroll
            for (int c = 0; c < 16; ++c) {
                const int cg = kh * 16 + c;
                short8 bf0 = *(const short8*)(hstage + cg * 1024 + lane * 16);
                short8 bf1 = *(const short8*)(hstage + 32768 + cg * 1024 + lane * 16);
                a00 = __builtin_amdgcn_mfma_f32_16x16x32_bf16(awreg[0][c], bf0, a00, 0, 0, 0);
                a01 = __builtin_amdgcn_mfma_f32_16x16x32_bf16(awreg[0][c], bf1, a01, 0, 0, 0);
                a10 = __builtin_amdgcn_mfma_f32_16x16x32_bf16(awreg[1][c], bf0, a10, 0, 0, 0);
                a11 = __builtin_amdgcn_mfma_f32_16x16x32_bf16(awreg[1][c], bf1, a11, 0, 0, 0);
            }
        }

        // C/D (HW-verified): col = lane&15, row = (lane>>4)*4 + reg
        {
            const int cn = lane & 15;
            const int rb = (lane >> 4) * 4;
#pragma unroll
            for (int r = 0; r < 4; ++r) {
                zb[kh][gate][ 0 + rb + r][ 0 + cn] = a00[r];
                zb[kh][gate][ 0 + rb + r][16 + cn] = a01[r];
                zb[kh][gate][16 + rb + r][ 0 + cn] = a10[r];
                zb[kh][gate][16 + rb + r][16 + cn] = a11[r];
            }
        }
        __syncthreads();

        // ---- elementwise epilogue: 2 cells/thread ----
        unsigned short hb[2];
#pragma unroll
        for (int q = 0; q < 2; ++q) {
            const int jl = 2 * aa + q;
            float zg = (zb[0][0][jl][nn] + zb[1][0][jl][nn]) + wxl[0][jl] * xv + bsl[0][nn];
            float zi = (zb[0][1][jl][nn] + zb[1][1][jl][nn]) + wxl[1][jl] * xv + bsl[1][nn];
            float zf = (zb[0][2][jl][nn] + zb[1][2][jl][nn]) + wxl[2][jl] * xv + bsl[2][nn];
            float zo = (zb[0][3][jl][nn] + zb[1][3][jl][nn]) + wxl[3][jl] * xv + bsl[3][nn];
            float g  = tanh_fast(zg);
            float ig = sigm_fast(zi);
            float fg = sigm_fast(zf);
            float og = sigm_fast(zo);
            creg[q] = g * ig + creg[q] * fg;
            float hn = tanh_fast(creg[q]) * og;
            hb[q] = bf16_bits(hn);
            if (t == T - 1) hfin[(j0 + jl) * B + (b0 + nn)] = hn;
        }
        // h store into next frag buffer: write-back L2 if local, else IC.
        // (mode1 stale-L2 safety: every byte of the slice is rewritten each
        //  step before the flag, and write-allocate merges make full-line
        //  content current regardless of underlying stale data.)
        {
            const unsigned val = (unsigned)hb[0] | ((unsigned)hb[1] << 16);
            short* fb = (short*)(frag + ((t + 1) & 1) * 524288);
            short* fdst = fb + ((2 * bt + (nn >> 4)) * 32 + jt) * 512
                        + ((aa >> 2) * 16 + (nn & 15)) * 8 + (aa & 3) * 2;
            if (lcl) {
                *(volatile unsigned*)fdst = val;
            } else {
                __hip_atomic_store((unsigned*)fdst, val, __ATOMIC_RELAXED,
                                   __HIP_MEMORY_SCOPE_AGENT);
            }
        }

        // ---- arrive: barrier drains every wave's store-acks (L2 or IC),
        // then one IC flag store (protocol unchanged) ----
        __syncthreads();
        if (tid == 0) {
            __asm__ volatile("s_waitcnt vmcnt(0)" ::: "memory");
            __hip_atomic_store(myflag, (unsigned)(t + 1), __ATOMIC_RELAXED,
                               __HIP_MEMORY_SCOPE_AGENT);
        }
    }
}

// ---------------- projection + softmax over batch --------------------------
__global__ __launch_bounds__(256) void lstm_final(
    const float* __restrict__ Wph, const float* __restrict__ hfin,
    const float* __restrict__ bp, float* __restrict__ out)
{
    __shared__ float sh[256];
    __shared__ float shm, shs;
    int c = blockIdx.x;
    int b = threadIdx.x;
    float acc = bp[b];
    const float* wr = Wph + c * H;
    for (int k = 0; k < H; ++k)
        acc += wr[k] * hfin[k * B + b];

    sh[b] = acc;
    __syncthreads();
    for (int s = 128; s > 0; s >>= 1) {
        if (b < s) sh[b] = fmaxf(sh[b], sh[b + s]);
        __syncthreads();
    }
    if (b == 0) shm = sh[0];
    __syncthreads();
    float e = expf(acc - shm);
    sh[b] = e;
    __syncthreads();
    for (int s = 128; s > 0; s >>= 1) {
        if (b < s) sh[b] += sh[b + s];
        __syncthreads();
    }
    if (b == 0) shs = sh[0];
    __syncthreads();
    out[b * NCLS + c] = e / shs;
}

extern "C" void kernel_launch(void* const* d_in, const int* in_sizes, int n_in,
                              void* d_out, int out_size, void* d_ws, size_t ws_size,
                              hipStream_t stream)
{
    const float* x   = (const float*)d_in[0];
    const float* Wgx = (const float*)d_in[1];
    const float* Wgh = (const float*)d_in[2];
    const float* Wix = (const float*)d_in[3];
    const float* Wih = (const float*)d_in[4];
    const float* Wfx = (const float*)d_in[5];
    const float* Wfh = (const float*)d_in[6];
    const float* Wox = (const float*)d_in[7];
    const float* Woh = (const float*)d_in[8];
    const float* Wph = (const float*)d_in[9];
    const float* bg  = (const float*)d_in[10];
    const float* bi  = (const float*)d_in[11];
    const float* bfv = (const float*)d_in[12];
    const float* bo  = (const float*)d_in[13];
    const float* bp  = (const float*)d_in[14];

    char* ws = (char*)d_ws;
    char* frag = ws;                                 // 1 MB (2 x 512 KB)
    unsigned* flags = (unsigned*)(ws + 1048576);     // 32 KB (256 x 128 B)
    unsigned* ctrl  = (unsigned*)(ws + 1081344);     // 4 KB
    float* hfin = (float*)(ws + 1085440);            // 1 MB

    // flags + ctrl zeroed (IC-side); frag needs no init (t=0 skip)
    hipMemsetAsync(flags, 0, 36864, stream);

    lstm_persist<<<256, 512, 0, stream>>>(
        x, Wgh, Wih, Wfh, Woh, Wgx, Wix, Wfx, Wox,
        bg, bi, bfv, bo, frag, flags, ctrl, hfin);

    lstm_final<<<NCLS, 256, 0, stream>>>(Wph, hfin, bp, (float*)d_out);
}